// Round 2
// baseline (304.103 us; speedup 1.0000x reference)
//
#include <hip/hip_runtime.h>
#include <math.h>
#include <stdint.h>

#define NQ 10
#define DEPTH 6

typedef _Float16 f16x8 __attribute__((ext_vector_type(8)));
typedef float f32x4 __attribute__((ext_vector_type(4)));

// ---------------------------------------------------------------------------
// Kernel 1: precompute the 60 Rot(phi,theta,omega) 2x2 complex matrices.
// ---------------------------------------------------------------------------
__global__ void prep_gates_kernel(const float* __restrict__ weights,
                                  float* __restrict__ gmat) {
    int idx = blockIdx.x * blockDim.x + threadIdx.x;
    if (idx >= DEPTH * NQ) return;
    float phi   = weights[idx * 3 + 0];
    float theta = weights[idx * 3 + 1];
    float omega = weights[idx * 3 + 2];
    float c = cosf(0.5f * theta), s = sinf(0.5f * theta);
    float ap = -0.5f * (phi + omega);
    float am = -0.5f * (phi - omega);
    float epr = cosf(ap), epi = sinf(ap);
    float emr = cosf(am), emi = sinf(am);
    float* g = gmat + idx * 8;
    g[0] =  epr * c;  g[1] =  epi * c;
    g[2] = -emr * s;  g[3] =  emi * s;
    g[4] =  emr * s;  g[5] =  emi * s;
    g[6] =  epr * c;  g[7] = -epi * c;
}

// ---------------------------------------------------------------------------
// Circuit core (verified in round 1): one wave holds 1024 amps.
// amp g: bits 0..3 = slot j, bits 4..9 = lane.
// ---------------------------------------------------------------------------
__device__ __forceinline__ void apply_1q_local(
    float (&ar)[16], float (&ai)[16], int q,
    float u00r, float u00i, float u01r, float u01i,
    float u10r, float u10i, float u11r, float u11i) {
#pragma unroll
    for (int j = 0; j < 16; ++j) {
        if ((j >> q) & 1) continue;
        int j1 = j | (1 << q);
        float a0r = ar[j],  a0i = ai[j];
        float a1r = ar[j1], a1i = ai[j1];
        ar[j]  = u00r*a0r - u00i*a0i + u01r*a1r - u01i*a1i;
        ai[j]  = u00r*a0i + u00i*a0r + u01r*a1i + u01i*a1r;
        ar[j1] = u10r*a0r - u10i*a0i + u11r*a1r - u11i*a1i;
        ai[j1] = u10r*a0i + u10i*a0r + u11r*a1i + u11i*a1r;
    }
}

__device__ __forceinline__ void apply_1q_lane(
    float (&ar)[16], float (&ai)[16], int q, int lane,
    float u00r, float u00i, float u01r, float u01i,
    float u10r, float u10i, float u11r, float u11i) {
    int  m  = 1 << (q - 4);
    bool hi = (lane >> (q - 4)) & 1;
    float car = hi ? u11r : u00r, cai = hi ? u11i : u00i;
    float cbr = hi ? u10r : u01r, cbi = hi ? u10i : u01i;
#pragma unroll
    for (int j = 0; j < 16; ++j) {
        float pr = __shfl_xor(ar[j], m, 64);
        float pi = __shfl_xor(ai[j], m, 64);
        float mr = ar[j], mi = ai[j];
        ar[j] = car*mr - cai*mi + cbr*pr - cbi*pi;
        ai[j] = car*mi + cai*mr + cbr*pi + cbi*pr;
    }
}

__device__ __forceinline__ void cnot_gate(
    float (&ar)[16], float (&ai)[16], int c, int t, int lane) {
    if (c < 4 && t < 4) {
#pragma unroll
        for (int j = 0; j < 16; ++j) {
            if (((j >> c) & 1) && !((j >> t) & 1)) {
                int j1 = j | (1 << t);
                float tr = ar[j]; ar[j] = ar[j1]; ar[j1] = tr;
                float ti = ai[j]; ai[j] = ai[j1]; ai[j1] = ti;
            }
        }
    } else if (c < 4) {
        int m = 1 << (t - 4);
#pragma unroll
        for (int j = 0; j < 16; ++j) {
            if ((j >> c) & 1) {
                ar[j] = __shfl_xor(ar[j], m, 64);
                ai[j] = __shfl_xor(ai[j], m, 64);
            }
        }
    } else if (t < 4) {
        bool cb = (lane >> (c - 4)) & 1;
#pragma unroll
        for (int j = 0; j < 16; ++j) {
            if (!((j >> t) & 1)) {
                int j1 = j | (1 << t);
                float lr = ar[j], li = ai[j], hr = ar[j1], hi2 = ai[j1];
                ar[j]  = cb ? hr : lr;  ai[j]  = cb ? hi2 : li;
                ar[j1] = cb ? lr : hr;  ai[j1] = cb ? li : hi2;
            }
        }
    } else {
        int  m  = 1 << (t - 4);
        bool cb = (lane >> (c - 4)) & 1;
#pragma unroll
        for (int j = 0; j < 16; ++j) {
            float pr = __shfl_xor(ar[j], m, 64);
            float pi = __shfl_xor(ai[j], m, 64);
            ar[j] = cb ? pr : ar[j];
            ai[j] = cb ? pi : ai[j];
        }
    }
}

template <int R>
__device__ __forceinline__ void cnot_ring(float (&ar)[16], float (&ai)[16], int lane) {
#pragma unroll
    for (int i = 0; i < NQ; ++i) cnot_gate(ar, ai, i, (i + R) % NQ, lane);
}

__device__ __forceinline__ void run_circuit(float (&ar)[16], float (&ai)[16],
                                            const float* __restrict__ gmat, int lane) {
    for (int l = 0; l < DEPTH; ++l) {
        const float* gl = gmat + l * (NQ * 8);
#pragma unroll
        for (int i = 0; i < NQ; ++i) {
            const float* g = gl + i * 8;
            float u00r = g[0], u00i = g[1], u01r = g[2], u01i = g[3];
            float u10r = g[4], u10i = g[5], u11r = g[6], u11i = g[7];
            if (i < 4)
                apply_1q_local(ar, ai, i, u00r,u00i,u01r,u01i,u10r,u10i,u11r,u11i);
            else
                apply_1q_lane(ar, ai, i, lane, u00r,u00i,u01r,u01i,u10r,u10i,u11r,u11i);
        }
        switch (l) {
            case 0: cnot_ring<1>(ar, ai, lane); break;
            case 1: cnot_ring<2>(ar, ai, lane); break;
            case 2: cnot_ring<3>(ar, ai, lane); break;
            case 3: cnot_ring<4>(ar, ai, lane); break;
            case 4: cnot_ring<5>(ar, ai, lane); break;
            default: cnot_ring<6>(ar, ai, lane); break;
        }
    }
}

__device__ __forceinline__ float wave_sum(float v) {
#pragma unroll
    for (int m = 1; m < 64; m <<= 1) v += __shfl_xor(v, m, 64);
    return v;
}

// ---------------------------------------------------------------------------
// Kernel 2: basis sim — wave h computes column h of U, writes row h of B'.
// B'[h][n], n = 2g+c (c=0 re, c=1 im), f16. Lane L writes n in [32L, 32L+32).
// ---------------------------------------------------------------------------
__global__ __launch_bounds__(256) void basis_sim_kernel(
    const float* __restrict__ gmat, _Float16* __restrict__ Bp) {
    int lane = threadIdx.x & 63;
    int wid  = threadIdx.x >> 6;
    int h    = blockIdx.x * 4 + wid;        // 0..1023

    float ar[16], ai[16];
#pragma unroll
    for (int j = 0; j < 16; ++j) {
        ar[j] = (lane == (h >> 4) && j == (h & 15)) ? 1.f : 0.f;
        ai[j] = 0.f;
    }
    run_circuit(ar, ai, gmat, lane);

    unsigned int buf[16];
#pragma unroll
    for (int j = 0; j < 16; ++j) {
        unsigned short r16 = __builtin_bit_cast(unsigned short, (_Float16)ar[j]);
        unsigned short i16 = __builtin_bit_cast(unsigned short, (_Float16)ai[j]);
        buf[j] = (unsigned int)r16 | ((unsigned int)i16 << 16);
    }
    uint4* dst = (uint4*)(Bp + (size_t)h * 2048 + 32 * lane);
#pragma unroll
    for (int k = 0; k < 4; ++k) {
        uint4 v; v.x = buf[k*4+0]; v.y = buf[k*4+1]; v.z = buf[k*4+2]; v.w = buf[k*4+3];
        dst[k] = v;
    }
}

// ---------------------------------------------------------------------------
// Kernel 3: transpose B' (1024 x 2048) -> Bt (2048 x 1024)
// ---------------------------------------------------------------------------
__global__ __launch_bounds__(256) void transpose_kernel(
    const unsigned short* __restrict__ src, unsigned short* __restrict__ dst) {
    __shared__ unsigned short tile[64][65];
    int bx = blockIdx.x;            // n-tile: 0..31
    int by = blockIdx.y;            // k-tile: 0..15
    int tx = threadIdx.x & 63;
    int ty = threadIdx.x >> 6;      // 0..3
#pragma unroll
    for (int i = 0; i < 16; ++i) {
        int r = ty + i * 4;
        tile[r][tx] = src[(size_t)(by*64 + r) * 2048 + bx*64 + tx];
    }
    __syncthreads();
#pragma unroll
    for (int i = 0; i < 16; ++i) {
        int r = ty + i * 4;
        dst[(size_t)(bx*64 + r) * 1024 + by*64 + tx] = tile[tx][r];
    }
}

// ---------------------------------------------------------------------------
// Kernel 4: projection + angles + product-state rows V[b][g] (f16).
// ---------------------------------------------------------------------------
__global__ __launch_bounds__(256) void proj_v_kernel(
    const float* __restrict__ x, const float* __restrict__ Wproj,
    _Float16* __restrict__ V, int B) {
    int lane = threadIdx.x & 63;
    int wid  = threadIdx.x >> 6;
    int b    = blockIdx.x * 4 + wid;
    if (b >= B) return;

    const float* xb = x + (size_t)b * 1024;
    float acc[NQ];
#pragma unroll
    for (int q = 0; q < NQ; ++q) acc[q] = 0.f;
#pragma unroll
    for (int k = 0; k < 16; ++k) {
        float xv = xb[k * 64 + lane];
#pragma unroll
        for (int q = 0; q < NQ; ++q)
            acc[q] = fmaf(xv, Wproj[q * 1024 + k * 64 + lane], acc[q]);
    }
#pragma unroll
    for (int q = 0; q < NQ; ++q) acc[q] = wave_sum(acc[q]);

    float cq[NQ], sq[NQ];
#pragma unroll
    for (int q = 0; q < NQ; ++q) {
        float ang = tanhf(acc[q]) * 1.57079632679489662f;
        cq[q] = cosf(0.5f * ang);
        sq[q] = sinf(0.5f * ang);
    }
    float laneprod = 1.f;
#pragma unroll
    for (int q = 4; q < NQ; ++q)
        laneprod *= ((lane >> (q - 4)) & 1) ? sq[q] : cq[q];

    unsigned int buf[8];
#pragma unroll
    for (int jj = 0; jj < 8; ++jj) {
        unsigned short h[2];
#pragma unroll
        for (int c = 0; c < 2; ++c) {
            int j = jj * 2 + c;
            float p = laneprod;
#pragma unroll
            for (int q = 0; q < 4; ++q) p *= ((j >> q) & 1) ? sq[q] : cq[q];
            h[c] = __builtin_bit_cast(unsigned short, (_Float16)p);
        }
        buf[jj] = (unsigned int)h[0] | ((unsigned int)h[1] << 16);
    }
    uint4* dst = (uint4*)(V + (size_t)b * 1024 + 16 * lane);
    uint4 v0; v0.x = buf[0]; v0.y = buf[1]; v0.z = buf[2]; v0.w = buf[3];
    uint4 v1; v1.x = buf[4]; v1.y = buf[5]; v1.z = buf[6]; v1.w = buf[7];
    dst[0] = v0; dst[1] = v1;
}

// ---------------------------------------------------------------------------
// Kernel 5: GEMM C(Mx2048) = V(Mx1024) @ Bt^T, f16 MFMA 16x16x32.
// 128x128 tile per block (4 waves, 64x64 each), BK=64, XOR-swizzled LDS.
// ---------------------------------------------------------------------------
__global__ __launch_bounds__(256) void gemm_kernel(
    const unsigned short* __restrict__ A,    // V
    const unsigned short* __restrict__ Bt,   // (2048,1024)
    _Float16* __restrict__ C) {              // (M,2048)
    __shared__ unsigned short As[128 * 64];
    __shared__ unsigned short Bs[128 * 64];
    int tid  = threadIdx.x;
    int lane = tid & 63;
    int w    = tid >> 6;
    int m0   = blockIdx.y * 128;
    int n0   = blockIdx.x * 128;
    int mh   = (w >> 1) * 64, nh = (w & 1) * 64;
    int quad = lane >> 4;
    int lrow = lane & 15;

    f32x4 acc[4][4];
#pragma unroll
    for (int mi = 0; mi < 4; ++mi)
#pragma unroll
        for (int ni = 0; ni < 4; ++ni)
            acc[mi][ni] = (f32x4){0.f, 0.f, 0.f, 0.f};

    for (int kt = 0; kt < 16; ++kt) {
        uint4 av[4], bv[4];
#pragma unroll
        for (int r = 0; r < 4; ++r) {
            int cc  = r * 256 + tid;
            int row = cc >> 3, c8 = cc & 7;
            av[r] = *(const uint4*)(A  + (size_t)(m0 + row) * 1024 + kt * 64 + c8 * 8);
            bv[r] = *(const uint4*)(Bt + (size_t)(n0 + row) * 1024 + kt * 64 + c8 * 8);
        }
        __syncthreads();
#pragma unroll
        for (int r = 0; r < 4; ++r) {
            int cc  = r * 256 + tid;
            int row = cc >> 3, c8x = (cc & 7) ^ (row & 7);
            *(uint4*)(As + row * 64 + c8x * 8) = av[r];
            *(uint4*)(Bs + row * 64 + c8x * 8) = bv[r];
        }
        __syncthreads();
#pragma unroll
        for (int kk = 0; kk < 2; ++kk) {
            f16x8 af[4], bf[4];
#pragma unroll
            for (int i = 0; i < 4; ++i) {
                int cxa = (kk * 4 + quad) ^ (lrow & 7);
                af[i] = *(const f16x8*)(As + (mh + i * 16 + lrow) * 64 + cxa * 8);
                bf[i] = *(const f16x8*)(Bs + (nh + i * 16 + lrow) * 64 + cxa * 8);
            }
#pragma unroll
            for (int mi = 0; mi < 4; ++mi)
#pragma unroll
                for (int ni = 0; ni < 4; ++ni)
                    acc[mi][ni] = __builtin_amdgcn_mfma_f32_16x16x32_f16(
                        af[mi], bf[ni], acc[mi][ni], 0, 0, 0);
        }
    }
#pragma unroll
    for (int mi = 0; mi < 4; ++mi)
#pragma unroll
        for (int ni = 0; ni < 4; ++ni)
#pragma unroll
            for (int r = 0; r < 4; ++r) {
                int m = m0 + mh + mi * 16 + quad * 4 + r;
                int n = n0 + nh + ni * 16 + lrow;
                C[(size_t)m * 2048 + n] = (_Float16)acc[mi][ni][r];
            }
}

// ---------------------------------------------------------------------------
// Kernel 6: p = re^2+im^2, Z_q signed sums, output head. One wave per row.
// ---------------------------------------------------------------------------
__global__ __launch_bounds__(256) void reduce_head_kernel(
    const _Float16* __restrict__ C, const float* __restrict__ Wout,
    const float* __restrict__ bout, float* __restrict__ out, int B) {
    int lane = threadIdx.x & 63;
    int wid  = threadIdx.x >> 6;
    int b    = blockIdx.x * 4 + wid;
    if (b >= B) return;

    const uint4* p4 = (const uint4*)(C + (size_t)b * 2048 + 32 * lane);
    float T = 0.f, S[4] = {0.f, 0.f, 0.f, 0.f};
#pragma unroll
    for (int c4 = 0; c4 < 4; ++c4) {
        uint4 v = p4[c4];
        unsigned int u4[4] = {v.x, v.y, v.z, v.w};
#pragma unroll
        for (int e = 0; e < 4; ++e) {
            unsigned int u = u4[e];
            int jj = c4 * 4 + e;                 // g = 16*lane + jj
            float re = (float)__builtin_bit_cast(_Float16, (unsigned short)(u & 0xffffu));
            float im = (float)__builtin_bit_cast(_Float16, (unsigned short)(u >> 16));
            float p = re * re + im * im;
            T += p;
#pragma unroll
            for (int q = 0; q < 4; ++q) S[q] += ((jj >> q) & 1) ? -p : p;
        }
    }
    float Zq[NQ];
#pragma unroll
    for (int q = 0; q < 4; ++q) Zq[q] = S[q];
#pragma unroll
    for (int q = 4; q < NQ; ++q) Zq[q] = ((lane >> (q - 4)) & 1) ? -T : T;
#pragma unroll
    for (int q = 0; q < NQ; ++q) Zq[q] = wave_sum(Zq[q]);

    if (lane < NQ) {
        float o = bout[lane];
#pragma unroll
        for (int q = 0; q < NQ; ++q) o = fmaf(Zq[q], Wout[lane * NQ + q], o);
        out[(size_t)b * NQ + lane] = o;
    }
}

// ---------------------------------------------------------------------------
// Fallback: round-1 monolithic kernel (verified; used if ws too small).
// ---------------------------------------------------------------------------
__global__ __launch_bounds__(256) void vqc_kernel(
    const float* __restrict__ x, const float* __restrict__ Wproj,
    const float* __restrict__ gmat, const float* __restrict__ Wout,
    const float* __restrict__ bout, float* __restrict__ out, int B) {
    int lane = threadIdx.x & 63;
    int wid  = threadIdx.x >> 6;
    int b    = blockIdx.x * 4 + wid;
    if (b >= B) return;

    const float* xb = x + (size_t)b * 1024;
    float acc[NQ];
#pragma unroll
    for (int q = 0; q < NQ; ++q) acc[q] = 0.f;
#pragma unroll
    for (int k = 0; k < 16; ++k) {
        float xv = xb[k * 64 + lane];
#pragma unroll
        for (int q = 0; q < NQ; ++q)
            acc[q] = fmaf(xv, Wproj[q * 1024 + k * 64 + lane], acc[q]);
    }
#pragma unroll
    for (int q = 0; q < NQ; ++q) acc[q] = wave_sum(acc[q]);

    float cq[NQ], sq[NQ];
#pragma unroll
    for (int q = 0; q < NQ; ++q) {
        float ang = tanhf(acc[q]) * 1.57079632679489662f;
        cq[q] = cosf(0.5f * ang);
        sq[q] = sinf(0.5f * ang);
    }
    float laneprod = 1.f;
#pragma unroll
    for (int q = 4; q < NQ; ++q)
        laneprod *= ((lane >> (q - 4)) & 1) ? sq[q] : cq[q];
    float ar[16], ai[16];
#pragma unroll
    for (int j = 0; j < 16; ++j) {
        float p = laneprod;
#pragma unroll
        for (int q = 0; q < 4; ++q) p *= ((j >> q) & 1) ? sq[q] : cq[q];
        ar[j] = p; ai[j] = 0.f;
    }
    run_circuit(ar, ai, gmat, lane);

    float T = 0.f, S[4] = {0.f, 0.f, 0.f, 0.f};
#pragma unroll
    for (int j = 0; j < 16; ++j) {
        float p = ar[j] * ar[j] + ai[j] * ai[j];
        T += p;
#pragma unroll
        for (int q = 0; q < 4; ++q) S[q] += ((j >> q) & 1) ? -p : p;
    }
    float Zq[NQ];
#pragma unroll
    for (int q = 0; q < 4; ++q) Zq[q] = S[q];
#pragma unroll
    for (int q = 4; q < NQ; ++q) Zq[q] = ((lane >> (q - 4)) & 1) ? -T : T;
#pragma unroll
    for (int q = 0; q < NQ; ++q) Zq[q] = wave_sum(Zq[q]);
    if (lane < NQ) {
        float o = bout[lane];
#pragma unroll
        for (int q = 0; q < NQ; ++q) o = fmaf(Zq[q], Wout[lane * NQ + q], o);
        out[(size_t)b * NQ + lane] = o;
    }
}

extern "C" void kernel_launch(void* const* d_in, const int* in_sizes, int n_in,
                              void* d_out, int out_size, void* d_ws, size_t ws_size,
                              hipStream_t stream) {
    const float* x       = (const float*)d_in[0];
    const float* Wproj   = (const float*)d_in[1];
    const float* weights = (const float*)d_in[2];
    const float* Wout    = (const float*)d_in[3];
    const float* bout    = (const float*)d_in[4];
    float* out = (float*)d_out;
    int B = in_sizes[0] / 1024;

    char* ws = (char*)d_ws;
    size_t off_Bp = 4096;
    size_t off_Bt = off_Bp + (size_t)1024 * 2048 * 2;
    size_t off_V  = off_Bt + (size_t)2048 * 1024 * 2;
    size_t off_C  = off_V + (size_t)B * 1024 * 2;
    size_t need   = off_C + (size_t)B * 2048 * 2;

    float* gmat = (float*)ws;
    prep_gates_kernel<<<1, 64, 0, stream>>>(weights, gmat);

    if (ws_size >= need && (B % 128) == 0) {
        _Float16* Bp = (_Float16*)(ws + off_Bp);
        _Float16* Bt = (_Float16*)(ws + off_Bt);
        _Float16* V  = (_Float16*)(ws + off_V);
        _Float16* C  = (_Float16*)(ws + off_C);

        basis_sim_kernel<<<256, 256, 0, stream>>>(gmat, Bp);
        transpose_kernel<<<dim3(32, 16), 256, 0, stream>>>(
            (const unsigned short*)Bp, (unsigned short*)Bt);
        proj_v_kernel<<<B / 4, 256, 0, stream>>>(x, Wproj, V, B);
        gemm_kernel<<<dim3(16, B / 128), 256, 0, stream>>>(
            (const unsigned short*)V, (const unsigned short*)Bt, C);
        reduce_head_kernel<<<B / 4, 256, 0, stream>>>(C, Wout, bout, out, B);
    } else {
        vqc_kernel<<<(B + 3) / 4, 256, 0, stream>>>(x, Wproj, gmat, Wout, bout, out, B);
    }
}

// Round 3
// 302.436 us; speedup vs baseline: 1.0055x; 1.0055x over previous
//
#include <hip/hip_runtime.h>
#include <math.h>
#include <stdint.h>

#define NQ 10
#define DEPTH 6

typedef _Float16 f16x8 __attribute__((ext_vector_type(8)));
typedef float f32x4 __attribute__((ext_vector_type(4)));

// ---------------------------------------------------------------------------
// Kernel 1: precompute the 60 Rot(phi,theta,omega) 2x2 complex matrices.
// ---------------------------------------------------------------------------
__global__ void prep_gates_kernel(const float* __restrict__ weights,
                                  float* __restrict__ gmat) {
    int idx = blockIdx.x * blockDim.x + threadIdx.x;
    if (idx >= DEPTH * NQ) return;
    float phi   = weights[idx * 3 + 0];
    float theta = weights[idx * 3 + 1];
    float omega = weights[idx * 3 + 2];
    float c = cosf(0.5f * theta), s = sinf(0.5f * theta);
    float ap = -0.5f * (phi + omega);
    float am = -0.5f * (phi - omega);
    float epr = cosf(ap), epi = sinf(ap);
    float emr = cosf(am), emi = sinf(am);
    float* g = gmat + idx * 8;
    g[0] =  epr * c;  g[1] =  epi * c;
    g[2] = -emr * s;  g[3] =  emi * s;
    g[4] =  emr * s;  g[5] =  emi * s;
    g[6] =  epr * c;  g[7] = -epi * c;
}

// ---------------------------------------------------------------------------
// Circuit core (verified round 1): one wave holds 1024 amps.
// amp g: bits 0..3 = slot j, bits 4..9 = lane.
// ---------------------------------------------------------------------------
__device__ __forceinline__ void apply_1q_local(
    float (&ar)[16], float (&ai)[16], int q,
    float u00r, float u00i, float u01r, float u01i,
    float u10r, float u10i, float u11r, float u11i) {
#pragma unroll
    for (int j = 0; j < 16; ++j) {
        if ((j >> q) & 1) continue;
        int j1 = j | (1 << q);
        float a0r = ar[j],  a0i = ai[j];
        float a1r = ar[j1], a1i = ai[j1];
        ar[j]  = u00r*a0r - u00i*a0i + u01r*a1r - u01i*a1i;
        ai[j]  = u00r*a0i + u00i*a0r + u01r*a1i + u01i*a1r;
        ar[j1] = u10r*a0r - u10i*a0i + u11r*a1r - u11i*a1i;
        ai[j1] = u10r*a0i + u10i*a0r + u11r*a1i + u11i*a1r;
    }
}

__device__ __forceinline__ void apply_1q_lane(
    float (&ar)[16], float (&ai)[16], int q, int lane,
    float u00r, float u00i, float u01r, float u01i,
    float u10r, float u10i, float u11r, float u11i) {
    int  m  = 1 << (q - 4);
    bool hi = (lane >> (q - 4)) & 1;
    float car = hi ? u11r : u00r, cai = hi ? u11i : u00i;
    float cbr = hi ? u10r : u01r, cbi = hi ? u10i : u01i;
#pragma unroll
    for (int j = 0; j < 16; ++j) {
        float pr = __shfl_xor(ar[j], m, 64);
        float pi = __shfl_xor(ai[j], m, 64);
        float mr = ar[j], mi = ai[j];
        ar[j] = car*mr - cai*mi + cbr*pr - cbi*pi;
        ai[j] = car*mi + cai*mr + cbr*pi + cbi*pr;
    }
}

__device__ __forceinline__ void cnot_gate(
    float (&ar)[16], float (&ai)[16], int c, int t, int lane) {
    if (c < 4 && t < 4) {
#pragma unroll
        for (int j = 0; j < 16; ++j) {
            if (((j >> c) & 1) && !((j >> t) & 1)) {
                int j1 = j | (1 << t);
                float tr = ar[j]; ar[j] = ar[j1]; ar[j1] = tr;
                float ti = ai[j]; ai[j] = ai[j1]; ai[j1] = ti;
            }
        }
    } else if (c < 4) {
        int m = 1 << (t - 4);
#pragma unroll
        for (int j = 0; j < 16; ++j) {
            if ((j >> c) & 1) {
                ar[j] = __shfl_xor(ar[j], m, 64);
                ai[j] = __shfl_xor(ai[j], m, 64);
            }
        }
    } else if (t < 4) {
        bool cb = (lane >> (c - 4)) & 1;
#pragma unroll
        for (int j = 0; j < 16; ++j) {
            if (!((j >> t) & 1)) {
                int j1 = j | (1 << t);
                float lr = ar[j], li = ai[j], hr = ar[j1], hi2 = ai[j1];
                ar[j]  = cb ? hr : lr;  ai[j]  = cb ? hi2 : li;
                ar[j1] = cb ? lr : hr;  ai[j1] = cb ? li : hi2;
            }
        }
    } else {
        int  m  = 1 << (t - 4);
        bool cb = (lane >> (c - 4)) & 1;
#pragma unroll
        for (int j = 0; j < 16; ++j) {
            float pr = __shfl_xor(ar[j], m, 64);
            float pi = __shfl_xor(ai[j], m, 64);
            ar[j] = cb ? pr : ar[j];
            ai[j] = cb ? pi : ai[j];
        }
    }
}

template <int R>
__device__ __forceinline__ void cnot_ring(float (&ar)[16], float (&ai)[16], int lane) {
#pragma unroll
    for (int i = 0; i < NQ; ++i) cnot_gate(ar, ai, i, (i + R) % NQ, lane);
}

__device__ __forceinline__ void run_circuit(float (&ar)[16], float (&ai)[16],
                                            const float* __restrict__ gmat, int lane) {
    for (int l = 0; l < DEPTH; ++l) {
        const float* gl = gmat + l * (NQ * 8);
#pragma unroll
        for (int i = 0; i < NQ; ++i) {
            const float* g = gl + i * 8;
            float u00r = g[0], u00i = g[1], u01r = g[2], u01i = g[3];
            float u10r = g[4], u10i = g[5], u11r = g[6], u11i = g[7];
            if (i < 4)
                apply_1q_local(ar, ai, i, u00r,u00i,u01r,u01i,u10r,u10i,u11r,u11i);
            else
                apply_1q_lane(ar, ai, i, lane, u00r,u00i,u01r,u01i,u10r,u10i,u11r,u11i);
        }
        switch (l) {
            case 0: cnot_ring<1>(ar, ai, lane); break;
            case 1: cnot_ring<2>(ar, ai, lane); break;
            case 2: cnot_ring<3>(ar, ai, lane); break;
            case 3: cnot_ring<4>(ar, ai, lane); break;
            case 4: cnot_ring<5>(ar, ai, lane); break;
            default: cnot_ring<6>(ar, ai, lane); break;
        }
    }
}

__device__ __forceinline__ float wave_sum(float v) {
#pragma unroll
    for (int m = 1; m < 64; m <<= 1) v += __shfl_xor(v, m, 64);
    return v;
}

// ---------------------------------------------------------------------------
// Kernel 2: basis sim — wave h computes column h of U, writes row h of B'.
// B'[h][n], n = 2g+c (c=0 re, c=1 im), f16.
// ---------------------------------------------------------------------------
__global__ __launch_bounds__(256) void basis_sim_kernel(
    const float* __restrict__ gmat, _Float16* __restrict__ Bp) {
    int lane = threadIdx.x & 63;
    int wid  = threadIdx.x >> 6;
    int h    = blockIdx.x * 4 + wid;

    float ar[16], ai[16];
#pragma unroll
    for (int j = 0; j < 16; ++j) {
        ar[j] = (lane == (h >> 4) && j == (h & 15)) ? 1.f : 0.f;
        ai[j] = 0.f;
    }
    run_circuit(ar, ai, gmat, lane);

    unsigned int buf[16];
#pragma unroll
    for (int j = 0; j < 16; ++j) {
        unsigned short r16 = __builtin_bit_cast(unsigned short, (_Float16)ar[j]);
        unsigned short i16 = __builtin_bit_cast(unsigned short, (_Float16)ai[j]);
        buf[j] = (unsigned int)r16 | ((unsigned int)i16 << 16);
    }
    uint4* dst = (uint4*)(Bp + (size_t)h * 2048 + 32 * lane);
#pragma unroll
    for (int k = 0; k < 4; ++k) {
        uint4 v; v.x = buf[k*4+0]; v.y = buf[k*4+1]; v.z = buf[k*4+2]; v.w = buf[k*4+3];
        dst[k] = v;
    }
}

// ---------------------------------------------------------------------------
// Kernel 3: transpose B' (1024 x 2048) -> Bt (2048 x 1024)
// ---------------------------------------------------------------------------
__global__ __launch_bounds__(256) void transpose_kernel(
    const unsigned short* __restrict__ src, unsigned short* __restrict__ dst) {
    __shared__ unsigned short tile[64][65];
    int bx = blockIdx.x;
    int by = blockIdx.y;
    int tx = threadIdx.x & 63;
    int ty = threadIdx.x >> 6;
#pragma unroll
    for (int i = 0; i < 16; ++i) {
        int r = ty + i * 4;
        tile[r][tx] = src[(size_t)(by*64 + r) * 2048 + bx*64 + tx];
    }
    __syncthreads();
#pragma unroll
    for (int i = 0; i < 16; ++i) {
        int r = ty + i * 4;
        dst[(size_t)(bx*64 + r) * 1024 + by*64 + tx] = tile[tx][r];
    }
}

// ---------------------------------------------------------------------------
// Kernel 4: projection + angles + product-state rows V[b][g] (f16).
// ---------------------------------------------------------------------------
__global__ __launch_bounds__(256) void proj_v_kernel(
    const float* __restrict__ x, const float* __restrict__ Wproj,
    _Float16* __restrict__ V, int B) {
    int lane = threadIdx.x & 63;
    int wid  = threadIdx.x >> 6;
    int b    = blockIdx.x * 4 + wid;
    if (b >= B) return;

    const float* xb = x + (size_t)b * 1024;
    float acc[NQ];
#pragma unroll
    for (int q = 0; q < NQ; ++q) acc[q] = 0.f;
#pragma unroll
    for (int k = 0; k < 16; ++k) {
        float xv = xb[k * 64 + lane];
#pragma unroll
        for (int q = 0; q < NQ; ++q)
            acc[q] = fmaf(xv, Wproj[q * 1024 + k * 64 + lane], acc[q]);
    }
#pragma unroll
    for (int q = 0; q < NQ; ++q) acc[q] = wave_sum(acc[q]);

    float cq[NQ], sq[NQ];
#pragma unroll
    for (int q = 0; q < NQ; ++q) {
        float ang = tanhf(acc[q]) * 1.57079632679489662f;
        cq[q] = cosf(0.5f * ang);
        sq[q] = sinf(0.5f * ang);
    }
    float laneprod = 1.f;
#pragma unroll
    for (int q = 4; q < NQ; ++q)
        laneprod *= ((lane >> (q - 4)) & 1) ? sq[q] : cq[q];

    unsigned int buf[8];
#pragma unroll
    for (int jj = 0; jj < 8; ++jj) {
        unsigned short h[2];
#pragma unroll
        for (int c = 0; c < 2; ++c) {
            int j = jj * 2 + c;
            float p = laneprod;
#pragma unroll
            for (int q = 0; q < 4; ++q) p *= ((j >> q) & 1) ? sq[q] : cq[q];
            h[c] = __builtin_bit_cast(unsigned short, (_Float16)p);
        }
        buf[jj] = (unsigned int)h[0] | ((unsigned int)h[1] << 16);
    }
    uint4* dst = (uint4*)(V + (size_t)b * 1024 + 16 * lane);
    uint4 v0; v0.x = buf[0]; v0.y = buf[1]; v0.z = buf[2]; v0.w = buf[3];
    uint4 v1; v1.x = buf[4]; v1.y = buf[5]; v1.z = buf[6]; v1.w = buf[7];
    dst[0] = v0; dst[1] = v1;
}

// ---------------------------------------------------------------------------
// Kernel 5: fused GEMM + |psi|^2 + partial-Z reduction.
// C-tile 128x128 never hits memory. Per block writes 128 rows x 8 floats:
//   [T, Z0, Z1, Z2, Z3, Z4, Z5, pad]  (q0..q5 fully reduced in-block)
// col n within block: n = nh + ni*16 + lrow; g' = n>>1
//   q0,q1,q2 <- lrow bits 1,2,3 (sign-stream butterfly)
//   q3,q4    <- ni bits 0,1    (in-register)
//   q5       <- wave half (w&1), combined via LDS
//   q6..q9   <- n-block index (combine kernel)
// ---------------------------------------------------------------------------
__global__ __launch_bounds__(256) void gemm_fused_kernel(
    const unsigned short* __restrict__ A,    // V (B,1024)
    const unsigned short* __restrict__ Bt,   // (2048,1024)
    float* __restrict__ Zpart) {             // (B,16,8)
    __shared__ unsigned short As[128 * 64];
    __shared__ unsigned short Bs[128 * 64];
    int tid  = threadIdx.x;
    int lane = tid & 63;
    int w    = tid >> 6;
    int m0   = blockIdx.x * 128;             // m fastest -> Bt stays L2-hot
    int n0   = blockIdx.y * 128;
    int mh   = (w >> 1) * 64, nh = (w & 1) * 64;
    int quad = lane >> 4;
    int lrow = lane & 15;

    f32x4 acc[4][4];
#pragma unroll
    for (int mi = 0; mi < 4; ++mi)
#pragma unroll
        for (int ni = 0; ni < 4; ++ni)
            acc[mi][ni] = (f32x4){0.f, 0.f, 0.f, 0.f};

    for (int kt = 0; kt < 16; ++kt) {
        uint4 av[4], bv[4];
#pragma unroll
        for (int r = 0; r < 4; ++r) {
            int cc  = r * 256 + tid;
            int row = cc >> 3, c8 = cc & 7;
            av[r] = *(const uint4*)(A  + (size_t)(m0 + row) * 1024 + kt * 64 + c8 * 8);
            bv[r] = *(const uint4*)(Bt + (size_t)(n0 + row) * 1024 + kt * 64 + c8 * 8);
        }
        __syncthreads();
#pragma unroll
        for (int r = 0; r < 4; ++r) {
            int cc  = r * 256 + tid;
            int row = cc >> 3, c8x = (cc & 7) ^ (row & 7);
            *(uint4*)(As + row * 64 + c8x * 8) = av[r];
            *(uint4*)(Bs + row * 64 + c8x * 8) = bv[r];
        }
        __syncthreads();
#pragma unroll
        for (int kk = 0; kk < 2; ++kk) {
            f16x8 af[4], bf[4];
#pragma unroll
            for (int i = 0; i < 4; ++i) {
                int cxa = (kk * 4 + quad) ^ (lrow & 7);
                af[i] = *(const f16x8*)(As + (mh + i * 16 + lrow) * 64 + cxa * 8);
                bf[i] = *(const f16x8*)(Bs + (nh + i * 16 + lrow) * 64 + cxa * 8);
            }
#pragma unroll
            for (int mi = 0; mi < 4; ++mi)
#pragma unroll
                for (int ni = 0; ni < 4; ++ni)
                    acc[mi][ni] = __builtin_amdgcn_mfma_f32_16x16x32_f16(
                        af[mi], bf[ni], acc[mi][ni], 0, 0, 0);
        }
    }

    // ---- fused epilogue: square + signed reduce ----
    __syncthreads();                         // done with As/Bs; reuse as Zs
    float* Zs = (float*)As;                  // [2][128][8] = 8KB
#pragma unroll
    for (int mi = 0; mi < 4; ++mi) {
#pragma unroll
        for (int r = 0; r < 4; ++r) {
            float p0 = acc[mi][0][r] * acc[mi][0][r];
            float p1 = acc[mi][1][r] * acc[mi][1][r];
            float p2 = acc[mi][2][r] * acc[mi][2][r];
            float p3 = acc[mi][3][r] * acc[mi][3][r];
            float t0 = (p0 + p1) + (p2 + p3);          // plain
            float t3 = (p0 - p1) + (p2 - p3);          // q3: ni bit0
            float t4 = (p0 + p1) - (p2 + p3);          // q4: ni bit1
            // butterfly over 16 lanes (lrow); xor1 = re/im pair (plain)
            t0 += __shfl_xor(t0, 1, 64);
            t3 += __shfl_xor(t3, 1, 64);
            t4 += __shfl_xor(t4, 1, 64);
            float u2 = __shfl_xor(t0, 2, 64);
            float ap = t0 + u2;
            float am = (lane & 2) ? u2 - t0 : t0 - u2;  // q0 stream
            t3 += __shfl_xor(t3, 2, 64);
            t4 += __shfl_xor(t4, 2, 64);
            float u4  = __shfl_xor(ap, 4, 64);
            float bpp = ap + u4;
            float bpm = (lane & 4) ? u4 - ap : ap - u4; // q1 stream
            float bmp = am + __shfl_xor(am, 4, 64);
            t3 += __shfl_xor(t3, 4, 64);
            t4 += __shfl_xor(t4, 4, 64);
            float u8 = __shfl_xor(bpp, 8, 64);
            float T  = bpp + u8;
            float Z2 = (lane & 8) ? u8 - bpp : bpp - u8; // q2 stream
            float Z1 = bpm + __shfl_xor(bpm, 8, 64);
            float Z0 = bmp + __shfl_xor(bmp, 8, 64);
            t3 += __shfl_xor(t3, 8, 64);
            t4 += __shfl_xor(t4, 8, 64);
            if (lrow == 0) {
                int row = mh + mi * 16 + quad * 4 + r;
                float* z = Zs + ((size_t)(w & 1) * 128 + row) * 8;
                z[0] = T;  z[1] = Z0; z[2] = Z1; z[3] = Z2;
                z[4] = t3; z[5] = t4;
            }
        }
    }
    __syncthreads();
    // combine the two nh-halves; q5 sign = nh half
    {
        int row  = tid >> 1, part = tid & 1;
        const float* za = Zs + (size_t)row * 8;
        const float* zb = Zs + (size_t)(128 + row) * 8;
        float o[4];
        if (part == 0) {
            o[0] = za[0] + zb[0];            // T
            o[1] = za[1] + zb[1];            // Z0
            o[2] = za[2] + zb[2];            // Z1
            o[3] = za[3] + zb[3];            // Z2
        } else {
            o[0] = za[4] + zb[4];            // Z3
            o[1] = za[5] + zb[5];            // Z4
            o[2] = za[0] - zb[0];            // Z5 = T(nh=0) - T(nh=64)
            o[3] = 0.f;
        }
        float4 v = {o[0], o[1], o[2], o[3]};
        *(float4*)(Zpart + ((size_t)(m0 + row) * 16 + blockIdx.y) * 8 + part * 4) = v;
    }
}

// ---------------------------------------------------------------------------
// Kernel 6: combine 16 n-tile partials -> Z_q -> output head. One wave/row.
// ---------------------------------------------------------------------------
__global__ __launch_bounds__(256) void combine_head_kernel(
    const float* __restrict__ Zpart, const float* __restrict__ Wout,
    const float* __restrict__ bout, float* __restrict__ out, int B) {
    int lane = threadIdx.x & 63;
    int wid  = threadIdx.x >> 6;
    int b    = blockIdx.x * 4 + wid;
    if (b >= B) return;

    float z[8];
    if (lane < 16) {
        const float4* p = (const float4*)(Zpart + ((size_t)b * 16 + lane) * 8);
        float4 a = p[0], c = p[1];
        z[0]=a.x; z[1]=a.y; z[2]=a.z; z[3]=a.w; z[4]=c.x; z[5]=c.y; z[6]=c.z; z[7]=c.w;
    } else {
#pragma unroll
        for (int i = 0; i < 8; ++i) z[i] = 0.f;
    }
    float Zq[NQ];
    // q0..q5: plain 16-lane reduce of z[1..6]
#pragma unroll
    for (int q = 0; q < 6; ++q) {
        float v = z[q + 1];
        v += __shfl_xor(v, 1, 64);
        v += __shfl_xor(v, 2, 64);
        v += __shfl_xor(v, 4, 64);
        v += __shfl_xor(v, 8, 64);
        Zq[q] = v;
    }
    // q6..q9: signed reduce of T over tile index (lane bits 0..3)
    {
        float T = z[0];
        float u1 = __shfl_xor(T, 1, 64);
        float P  = T + u1;
        float M  = (lane & 1) ? u1 - T : T - u1;          // q6
        float u2 = __shfl_xor(P, 2, 64);
        float PP = P + u2;
        float PM = (lane & 2) ? u2 - P : P - u2;          // q7
        float MP = M + __shfl_xor(M, 2, 64);
        float u4  = __shfl_xor(PP, 4, 64);
        float PPP = PP + u4;
        float PPM = (lane & 4) ? u4 - PP : PP - u4;       // q8
        float PMP = PM + __shfl_xor(PM, 4, 64);
        float MPP = MP + __shfl_xor(MP, 4, 64);
        float u8 = __shfl_xor(PPP, 8, 64);
        Zq[9] = (lane & 8) ? u8 - PPP : PPP - u8;
        Zq[8] = PPM + __shfl_xor(PPM, 8, 64);
        Zq[7] = PMP + __shfl_xor(PMP, 8, 64);
        Zq[6] = MPP + __shfl_xor(MPP, 8, 64);
    }
    if (lane < NQ) {
        float o = bout[lane];
#pragma unroll
        for (int q = 0; q < NQ; ++q) o = fmaf(Zq[q], Wout[lane * NQ + q], o);
        out[(size_t)b * NQ + lane] = o;
    }
}

// ---------------------------------------------------------------------------
// Fallback: round-1 monolithic kernel (verified).
// ---------------------------------------------------------------------------
__global__ __launch_bounds__(256) void vqc_kernel(
    const float* __restrict__ x, const float* __restrict__ Wproj,
    const float* __restrict__ gmat, const float* __restrict__ Wout,
    const float* __restrict__ bout, float* __restrict__ out, int B) {
    int lane = threadIdx.x & 63;
    int wid  = threadIdx.x >> 6;
    int b    = blockIdx.x * 4 + wid;
    if (b >= B) return;

    const float* xb = x + (size_t)b * 1024;
    float acc[NQ];
#pragma unroll
    for (int q = 0; q < NQ; ++q) acc[q] = 0.f;
#pragma unroll
    for (int k = 0; k < 16; ++k) {
        float xv = xb[k * 64 + lane];
#pragma unroll
        for (int q = 0; q < NQ; ++q)
            acc[q] = fmaf(xv, Wproj[q * 1024 + k * 64 + lane], acc[q]);
    }
#pragma unroll
    for (int q = 0; q < NQ; ++q) acc[q] = wave_sum(acc[q]);

    float cq[NQ], sq[NQ];
#pragma unroll
    for (int q = 0; q < NQ; ++q) {
        float ang = tanhf(acc[q]) * 1.57079632679489662f;
        cq[q] = cosf(0.5f * ang);
        sq[q] = sinf(0.5f * ang);
    }
    float laneprod = 1.f;
#pragma unroll
    for (int q = 4; q < NQ; ++q)
        laneprod *= ((lane >> (q - 4)) & 1) ? sq[q] : cq[q];
    float ar[16], ai[16];
#pragma unroll
    for (int j = 0; j < 16; ++j) {
        float p = laneprod;
#pragma unroll
        for (int q = 0; q < 4; ++q) p *= ((j >> q) & 1) ? sq[q] : cq[q];
        ar[j] = p; ai[j] = 0.f;
    }
    run_circuit(ar, ai, gmat, lane);

    float T = 0.f, S[4] = {0.f, 0.f, 0.f, 0.f};
#pragma unroll
    for (int j = 0; j < 16; ++j) {
        float p = ar[j] * ar[j] + ai[j] * ai[j];
        T += p;
#pragma unroll
        for (int q = 0; q < 4; ++q) S[q] += ((j >> q) & 1) ? -p : p;
    }
    float Zq[NQ];
#pragma unroll
    for (int q = 0; q < 4; ++q) Zq[q] = S[q];
#pragma unroll
    for (int q = 4; q < NQ; ++q) Zq[q] = ((lane >> (q - 4)) & 1) ? -T : T;
#pragma unroll
    for (int q = 0; q < NQ; ++q) Zq[q] = wave_sum(Zq[q]);
    if (lane < NQ) {
        float o = bout[lane];
#pragma unroll
        for (int q = 0; q < NQ; ++q) o = fmaf(Zq[q], Wout[lane * NQ + q], o);
        out[(size_t)b * NQ + lane] = o;
    }
}

extern "C" void kernel_launch(void* const* d_in, const int* in_sizes, int n_in,
                              void* d_out, int out_size, void* d_ws, size_t ws_size,
                              hipStream_t stream) {
    const float* x       = (const float*)d_in[0];
    const float* Wproj   = (const float*)d_in[1];
    const float* weights = (const float*)d_in[2];
    const float* Wout    = (const float*)d_in[3];
    const float* bout    = (const float*)d_in[4];
    float* out = (float*)d_out;
    int B = in_sizes[0] / 1024;

    char* ws = (char*)d_ws;
    size_t off_Bp = 4096;
    size_t off_Bt = off_Bp + (size_t)1024 * 2048 * 2;
    size_t off_V  = off_Bt + (size_t)2048 * 1024 * 2;
    size_t off_Z  = off_V  + (size_t)B * 1024 * 2;
    size_t need   = off_Z  + (size_t)B * 16 * 8 * 4;

    float* gmat = (float*)ws;
    prep_gates_kernel<<<1, 64, 0, stream>>>(weights, gmat);

    if (ws_size >= need && (B % 128) == 0) {
        _Float16* Bp = (_Float16*)(ws + off_Bp);
        _Float16* Bt = (_Float16*)(ws + off_Bt);
        _Float16* V  = (_Float16*)(ws + off_V);
        float*  Zprt = (float*)(ws + off_Z);

        basis_sim_kernel<<<256, 256, 0, stream>>>(gmat, Bp);
        transpose_kernel<<<dim3(32, 16), 256, 0, stream>>>(
            (const unsigned short*)Bp, (unsigned short*)Bt);
        proj_v_kernel<<<B / 4, 256, 0, stream>>>(x, Wproj, V, B);
        gemm_fused_kernel<<<dim3(B / 128, 16), 256, 0, stream>>>(
            (const unsigned short*)V, (const unsigned short*)Bt, Zprt);
        combine_head_kernel<<<B / 4, 256, 0, stream>>>(Zprt, Wout, bout, out, B);
    } else {
        vqc_kernel<<<(B + 3) / 4, 256, 0, stream>>>(x, Wproj, gmat, Wout, bout, out, B);
    }
}

// Round 4
// 199.293 us; speedup vs baseline: 1.5259x; 1.5175x over previous
//
#include <hip/hip_runtime.h>
#include <math.h>
#include <stdint.h>

#define NQ 10
#define DEPTH 6

typedef _Float16 f16x8 __attribute__((ext_vector_type(8)));
typedef float f32x4 __attribute__((ext_vector_type(4)));

typedef __attribute__((address_space(3))) unsigned int lds_u32;
typedef const __attribute__((address_space(1))) unsigned int glb_u32;

// async global->LDS, 16 B per lane; LDS dest = wave-uniform base + lane*16
__device__ __forceinline__ void async_load16(const unsigned short* g, unsigned short* l) {
    __builtin_amdgcn_global_load_lds((glb_u32*)g, (lds_u32*)l, 16, 0, 0);
}

// ---------------------------------------------------------------------------
// Kernel 1: precompute the 60 Rot(phi,theta,omega) 2x2 complex matrices.
// ---------------------------------------------------------------------------
__global__ void prep_gates_kernel(const float* __restrict__ weights,
                                  float* __restrict__ gmat) {
    int idx = blockIdx.x * blockDim.x + threadIdx.x;
    if (idx >= DEPTH * NQ) return;
    float phi   = weights[idx * 3 + 0];
    float theta = weights[idx * 3 + 1];
    float omega = weights[idx * 3 + 2];
    float c = cosf(0.5f * theta), s = sinf(0.5f * theta);
    float ap = -0.5f * (phi + omega);
    float am = -0.5f * (phi - omega);
    float epr = cosf(ap), epi = sinf(ap);
    float emr = cosf(am), emi = sinf(am);
    float* g = gmat + idx * 8;
    g[0] =  epr * c;  g[1] =  epi * c;
    g[2] = -emr * s;  g[3] =  emi * s;
    g[4] =  emr * s;  g[5] =  emi * s;
    g[6] =  epr * c;  g[7] = -epi * c;
}

// ---------------------------------------------------------------------------
// Circuit core (verified round 1): one wave holds 1024 amps.
// ---------------------------------------------------------------------------
__device__ __forceinline__ void apply_1q_local(
    float (&ar)[16], float (&ai)[16], int q,
    float u00r, float u00i, float u01r, float u01i,
    float u10r, float u10i, float u11r, float u11i) {
#pragma unroll
    for (int j = 0; j < 16; ++j) {
        if ((j >> q) & 1) continue;
        int j1 = j | (1 << q);
        float a0r = ar[j],  a0i = ai[j];
        float a1r = ar[j1], a1i = ai[j1];
        ar[j]  = u00r*a0r - u00i*a0i + u01r*a1r - u01i*a1i;
        ai[j]  = u00r*a0i + u00i*a0r + u01r*a1i + u01i*a1r;
        ar[j1] = u10r*a0r - u10i*a0i + u11r*a1r - u11i*a1i;
        ai[j1] = u10r*a0i + u10i*a0r + u11r*a1i + u11i*a1r;
    }
}

__device__ __forceinline__ void apply_1q_lane(
    float (&ar)[16], float (&ai)[16], int q, int lane,
    float u00r, float u00i, float u01r, float u01i,
    float u10r, float u10i, float u11r, float u11i) {
    int  m  = 1 << (q - 4);
    bool hi = (lane >> (q - 4)) & 1;
    float car = hi ? u11r : u00r, cai = hi ? u11i : u00i;
    float cbr = hi ? u10r : u01r, cbi = hi ? u10i : u01i;
#pragma unroll
    for (int j = 0; j < 16; ++j) {
        float pr = __shfl_xor(ar[j], m, 64);
        float pi = __shfl_xor(ai[j], m, 64);
        float mr = ar[j], mi = ai[j];
        ar[j] = car*mr - cai*mi + cbr*pr - cbi*pi;
        ai[j] = car*mi + cai*mr + cbr*pi + cbi*pr;
    }
}

__device__ __forceinline__ void cnot_gate(
    float (&ar)[16], float (&ai)[16], int c, int t, int lane) {
    if (c < 4 && t < 4) {
#pragma unroll
        for (int j = 0; j < 16; ++j) {
            if (((j >> c) & 1) && !((j >> t) & 1)) {
                int j1 = j | (1 << t);
                float tr = ar[j]; ar[j] = ar[j1]; ar[j1] = tr;
                float ti = ai[j]; ai[j] = ai[j1]; ai[j1] = ti;
            }
        }
    } else if (c < 4) {
        int m = 1 << (t - 4);
#pragma unroll
        for (int j = 0; j < 16; ++j) {
            if ((j >> c) & 1) {
                ar[j] = __shfl_xor(ar[j], m, 64);
                ai[j] = __shfl_xor(ai[j], m, 64);
            }
        }
    } else if (t < 4) {
        bool cb = (lane >> (c - 4)) & 1;
#pragma unroll
        for (int j = 0; j < 16; ++j) {
            if (!((j >> t) & 1)) {
                int j1 = j | (1 << t);
                float lr = ar[j], li = ai[j], hr = ar[j1], hi2 = ai[j1];
                ar[j]  = cb ? hr : lr;  ai[j]  = cb ? hi2 : li;
                ar[j1] = cb ? lr : hr;  ai[j1] = cb ? li : hi2;
            }
        }
    } else {
        int  m  = 1 << (t - 4);
        bool cb = (lane >> (c - 4)) & 1;
#pragma unroll
        for (int j = 0; j < 16; ++j) {
            float pr = __shfl_xor(ar[j], m, 64);
            float pi = __shfl_xor(ai[j], m, 64);
            ar[j] = cb ? pr : ar[j];
            ai[j] = cb ? pi : ai[j];
        }
    }
}

template <int R>
__device__ __forceinline__ void cnot_ring(float (&ar)[16], float (&ai)[16], int lane) {
#pragma unroll
    for (int i = 0; i < NQ; ++i) cnot_gate(ar, ai, i, (i + R) % NQ, lane);
}

__device__ __forceinline__ void run_circuit(float (&ar)[16], float (&ai)[16],
                                            const float* __restrict__ gmat, int lane) {
    for (int l = 0; l < DEPTH; ++l) {
        const float* gl = gmat + l * (NQ * 8);
#pragma unroll
        for (int i = 0; i < NQ; ++i) {
            const float* g = gl + i * 8;
            float u00r = g[0], u00i = g[1], u01r = g[2], u01i = g[3];
            float u10r = g[4], u10i = g[5], u11r = g[6], u11i = g[7];
            if (i < 4)
                apply_1q_local(ar, ai, i, u00r,u00i,u01r,u01i,u10r,u10i,u11r,u11i);
            else
                apply_1q_lane(ar, ai, i, lane, u00r,u00i,u01r,u01i,u10r,u10i,u11r,u11i);
        }
        switch (l) {
            case 0: cnot_ring<1>(ar, ai, lane); break;
            case 1: cnot_ring<2>(ar, ai, lane); break;
            case 2: cnot_ring<3>(ar, ai, lane); break;
            case 3: cnot_ring<4>(ar, ai, lane); break;
            case 4: cnot_ring<5>(ar, ai, lane); break;
            default: cnot_ring<6>(ar, ai, lane); break;
        }
    }
}

__device__ __forceinline__ float wave_sum(float v) {
#pragma unroll
    for (int m = 1; m < 64; m <<= 1) v += __shfl_xor(v, m, 64);
    return v;
}

// ---------------------------------------------------------------------------
// Kernel 2: basis sim — wave h computes column h of U, writes row h of B'.
// ---------------------------------------------------------------------------
__global__ __launch_bounds__(256) void basis_sim_kernel(
    const float* __restrict__ gmat, _Float16* __restrict__ Bp) {
    int lane = threadIdx.x & 63;
    int wid  = threadIdx.x >> 6;
    int h    = blockIdx.x * 4 + wid;

    float ar[16], ai[16];
#pragma unroll
    for (int j = 0; j < 16; ++j) {
        ar[j] = (lane == (h >> 4) && j == (h & 15)) ? 1.f : 0.f;
        ai[j] = 0.f;
    }
    run_circuit(ar, ai, gmat, lane);

    unsigned int buf[16];
#pragma unroll
    for (int j = 0; j < 16; ++j) {
        unsigned short r16 = __builtin_bit_cast(unsigned short, (_Float16)ar[j]);
        unsigned short i16 = __builtin_bit_cast(unsigned short, (_Float16)ai[j]);
        buf[j] = (unsigned int)r16 | ((unsigned int)i16 << 16);
    }
    uint4* dst = (uint4*)(Bp + (size_t)h * 2048 + 32 * lane);
#pragma unroll
    for (int k = 0; k < 4; ++k) {
        uint4 v; v.x = buf[k*4+0]; v.y = buf[k*4+1]; v.z = buf[k*4+2]; v.w = buf[k*4+3];
        dst[k] = v;
    }
}

// ---------------------------------------------------------------------------
// Kernel 3: transpose B' (1024 x 2048) -> Bt (2048 x 1024)
// ---------------------------------------------------------------------------
__global__ __launch_bounds__(256) void transpose_kernel(
    const unsigned short* __restrict__ src, unsigned short* __restrict__ dst) {
    __shared__ unsigned short tile[64][65];
    int bx = blockIdx.x;
    int by = blockIdx.y;
    int tx = threadIdx.x & 63;
    int ty = threadIdx.x >> 6;
#pragma unroll
    for (int i = 0; i < 16; ++i) {
        int r = ty + i * 4;
        tile[r][tx] = src[(size_t)(by*64 + r) * 2048 + bx*64 + tx];
    }
    __syncthreads();
#pragma unroll
    for (int i = 0; i < 16; ++i) {
        int r = ty + i * 4;
        dst[(size_t)(bx*64 + r) * 1024 + by*64 + tx] = tile[tx][r];
    }
}

// ---------------------------------------------------------------------------
// Kernel 4: projection + angles + product-state rows V[b][g] (f16).
// ---------------------------------------------------------------------------
__global__ __launch_bounds__(256) void proj_v_kernel(
    const float* __restrict__ x, const float* __restrict__ Wproj,
    _Float16* __restrict__ V, int B) {
    int lane = threadIdx.x & 63;
    int wid  = threadIdx.x >> 6;
    int b    = blockIdx.x * 4 + wid;
    if (b >= B) return;

    const float* xb = x + (size_t)b * 1024;
    float acc[NQ];
#pragma unroll
    for (int q = 0; q < NQ; ++q) acc[q] = 0.f;
#pragma unroll
    for (int k = 0; k < 16; ++k) {
        float xv = xb[k * 64 + lane];
#pragma unroll
        for (int q = 0; q < NQ; ++q)
            acc[q] = fmaf(xv, Wproj[q * 1024 + k * 64 + lane], acc[q]);
    }
#pragma unroll
    for (int q = 0; q < NQ; ++q) acc[q] = wave_sum(acc[q]);

    float cq[NQ], sq[NQ];
#pragma unroll
    for (int q = 0; q < NQ; ++q) {
        float ang = tanhf(acc[q]) * 1.57079632679489662f;
        cq[q] = cosf(0.5f * ang);
        sq[q] = sinf(0.5f * ang);
    }
    float laneprod = 1.f;
#pragma unroll
    for (int q = 4; q < NQ; ++q)
        laneprod *= ((lane >> (q - 4)) & 1) ? sq[q] : cq[q];

    unsigned int buf[8];
#pragma unroll
    for (int jj = 0; jj < 8; ++jj) {
        unsigned short h[2];
#pragma unroll
        for (int c = 0; c < 2; ++c) {
            int j = jj * 2 + c;
            float p = laneprod;
#pragma unroll
            for (int q = 0; q < 4; ++q) p *= ((j >> q) & 1) ? sq[q] : cq[q];
            h[c] = __builtin_bit_cast(unsigned short, (_Float16)p);
        }
        buf[jj] = (unsigned int)h[0] | ((unsigned int)h[1] << 16);
    }
    uint4* dst = (uint4*)(V + (size_t)b * 1024 + 16 * lane);
    uint4 v0; v0.x = buf[0]; v0.y = buf[1]; v0.z = buf[2]; v0.w = buf[3];
    uint4 v1; v1.x = buf[4]; v1.y = buf[5]; v1.z = buf[6]; v1.w = buf[7];
    dst[0] = v0; dst[1] = v1;
}

// ---------------------------------------------------------------------------
// Kernel 5: fused GEMM + |psi|^2 + partial-Z reduction, m97-style staging.
// global_load_lds width=16 writes LDS at (wave base + lane*16); per-lane
// global chunk permutation (lane&7)^(lane>>3) realizes the XOR-swizzled
// LDS layout: LDS[row][c8] = global chunk c8 ^ (row&7). Coalescing kept
// (each 8-lane group covers one 128B window).
// ---------------------------------------------------------------------------
__global__ __launch_bounds__(256) void gemm_fused_kernel(
    const unsigned short* __restrict__ A,    // V (B,1024)
    const unsigned short* __restrict__ Bt,   // (2048,1024)
    float* __restrict__ Zpart) {             // (B,16,8)
    __shared__ unsigned short As[128 * 64];
    __shared__ unsigned short Bs[128 * 64];
    int tid  = threadIdx.x;
    int lane = tid & 63;
    int w    = tid >> 6;
    int m0   = blockIdx.x * 128;             // m fastest -> Bt tile L2-hot
    int n0   = blockIdx.y * 128;
    int mh   = (w >> 1) * 64, nh = (w & 1) * 64;
    int quad = lane >> 4;
    int lrow = lane & 15;

    // per-lane source offsets for async staging
    int srow  = (lane >> 3);                 // row within 8-row slab
    int schnk = (lane & 7) ^ srow;           // permuted 16B chunk

    f32x4 acc[4][4];
#pragma unroll
    for (int mi = 0; mi < 4; ++mi)
#pragma unroll
        for (int ni = 0; ni < 4; ++ni)
            acc[mi][ni] = (f32x4){0.f, 0.f, 0.f, 0.f};

    for (int kt = 0; kt < 16; ++kt) {
        if (kt) __syncthreads();             // everyone done reading old tile
#pragma unroll
        for (int r = 0; r < 4; ++r) {
            int s   = w * 4 + r;             // slab: rows [s*8, s*8+8)
            int row = s * 8 + srow;
            async_load16(A  + (size_t)(m0 + row) * 1024 + kt * 64 + schnk * 8,
                         As + s * 512);
            async_load16(Bt + (size_t)(n0 + row) * 1024 + kt * 64 + schnk * 8,
                         Bs + s * 512);
        }
        asm volatile("s_waitcnt vmcnt(0)" ::: "memory");
        __syncthreads();
#pragma unroll
        for (int kk = 0; kk < 2; ++kk) {
            f16x8 af[4], bf[4];
#pragma unroll
            for (int i = 0; i < 4; ++i) {
                int cxa = (kk * 4 + quad) ^ (lrow & 7);
                af[i] = *(const f16x8*)(As + (mh + i * 16 + lrow) * 64 + cxa * 8);
                bf[i] = *(const f16x8*)(Bs + (nh + i * 16 + lrow) * 64 + cxa * 8);
            }
#pragma unroll
            for (int mi = 0; mi < 4; ++mi)
#pragma unroll
                for (int ni = 0; ni < 4; ++ni)
                    acc[mi][ni] = __builtin_amdgcn_mfma_f32_16x16x32_f16(
                        af[mi], bf[ni], acc[mi][ni], 0, 0, 0);
        }
    }

    // ---- fused epilogue: square + signed reduce (verified round 3) ----
    __syncthreads();
    float* Zs = (float*)As;
#pragma unroll
    for (int mi = 0; mi < 4; ++mi) {
#pragma unroll
        for (int r = 0; r < 4; ++r) {
            float p0 = acc[mi][0][r] * acc[mi][0][r];
            float p1 = acc[mi][1][r] * acc[mi][1][r];
            float p2 = acc[mi][2][r] * acc[mi][2][r];
            float p3 = acc[mi][3][r] * acc[mi][3][r];
            float t0 = (p0 + p1) + (p2 + p3);
            float t3 = (p0 - p1) + (p2 - p3);
            float t4 = (p0 + p1) - (p2 + p3);
            t0 += __shfl_xor(t0, 1, 64);
            t3 += __shfl_xor(t3, 1, 64);
            t4 += __shfl_xor(t4, 1, 64);
            float u2 = __shfl_xor(t0, 2, 64);
            float ap = t0 + u2;
            float am = (lane & 2) ? u2 - t0 : t0 - u2;
            t3 += __shfl_xor(t3, 2, 64);
            t4 += __shfl_xor(t4, 2, 64);
            float u4  = __shfl_xor(ap, 4, 64);
            float bpp = ap + u4;
            float bpm = (lane & 4) ? u4 - ap : ap - u4;
            float bmp = am + __shfl_xor(am, 4, 64);
            t3 += __shfl_xor(t3, 4, 64);
            t4 += __shfl_xor(t4, 4, 64);
            float u8 = __shfl_xor(bpp, 8, 64);
            float T  = bpp + u8;
            float Z2 = (lane & 8) ? u8 - bpp : bpp - u8;
            float Z1 = bpm + __shfl_xor(bpm, 8, 64);
            float Z0 = bmp + __shfl_xor(bmp, 8, 64);
            t3 += __shfl_xor(t3, 8, 64);
            t4 += __shfl_xor(t4, 8, 64);
            if (lrow == 0) {
                int row = mh + mi * 16 + quad * 4 + r;
                float* z = Zs + ((size_t)(w & 1) * 128 + row) * 8;
                z[0] = T;  z[1] = Z0; z[2] = Z1; z[3] = Z2;
                z[4] = t3; z[5] = t4;
            }
        }
    }
    __syncthreads();
    {
        int row  = tid >> 1, part = tid & 1;
        const float* za = Zs + (size_t)row * 8;
        const float* zb = Zs + (size_t)(128 + row) * 8;
        float o[4];
        if (part == 0) {
            o[0] = za[0] + zb[0];
            o[1] = za[1] + zb[1];
            o[2] = za[2] + zb[2];
            o[3] = za[3] + zb[3];
        } else {
            o[0] = za[4] + zb[4];
            o[1] = za[5] + zb[5];
            o[2] = za[0] - zb[0];
            o[3] = 0.f;
        }
        float4 v = {o[0], o[1], o[2], o[3]};
        *(float4*)(Zpart + ((size_t)(m0 + row) * 16 + blockIdx.y) * 8 + part * 4) = v;
    }
}

// ---------------------------------------------------------------------------
// Kernel 6: combine 16 n-tile partials -> Z_q -> output head.
// ---------------------------------------------------------------------------
__global__ __launch_bounds__(256) void combine_head_kernel(
    const float* __restrict__ Zpart, const float* __restrict__ Wout,
    const float* __restrict__ bout, float* __restrict__ out, int B) {
    int lane = threadIdx.x & 63;
    int wid  = threadIdx.x >> 6;
    int b    = blockIdx.x * 4 + wid;
    if (b >= B) return;

    float z[8];
    if (lane < 16) {
        const float4* p = (const float4*)(Zpart + ((size_t)b * 16 + lane) * 8);
        float4 a = p[0], c = p[1];
        z[0]=a.x; z[1]=a.y; z[2]=a.z; z[3]=a.w; z[4]=c.x; z[5]=c.y; z[6]=c.z; z[7]=c.w;
    } else {
#pragma unroll
        for (int i = 0; i < 8; ++i) z[i] = 0.f;
    }
    float Zq[NQ];
#pragma unroll
    for (int q = 0; q < 6; ++q) {
        float v = z[q + 1];
        v += __shfl_xor(v, 1, 64);
        v += __shfl_xor(v, 2, 64);
        v += __shfl_xor(v, 4, 64);
        v += __shfl_xor(v, 8, 64);
        Zq[q] = v;
    }
    {
        float T = z[0];
        float u1 = __shfl_xor(T, 1, 64);
        float P  = T + u1;
        float M  = (lane & 1) ? u1 - T : T - u1;
        float u2 = __shfl_xor(P, 2, 64);
        float PP = P + u2;
        float PM = (lane & 2) ? u2 - P : P - u2;
        float MP = M + __shfl_xor(M, 2, 64);
        float u4  = __shfl_xor(PP, 4, 64);
        float PPP = PP + u4;
        float PPM = (lane & 4) ? u4 - PP : PP - u4;
        float PMP = PM + __shfl_xor(PM, 4, 64);
        float MPP = MP + __shfl_xor(MP, 4, 64);
        float u8 = __shfl_xor(PPP, 8, 64);
        Zq[9] = (lane & 8) ? u8 - PPP : PPP - u8;
        Zq[8] = PPM + __shfl_xor(PPM, 8, 64);
        Zq[7] = PMP + __shfl_xor(PMP, 8, 64);
        Zq[6] = MPP + __shfl_xor(MPP, 8, 64);
    }
    if (lane < NQ) {
        float o = bout[lane];
#pragma unroll
        for (int q = 0; q < NQ; ++q) o = fmaf(Zq[q], Wout[lane * NQ + q], o);
        out[(size_t)b * NQ + lane] = o;
    }
}

// ---------------------------------------------------------------------------
// Fallback: round-1 monolithic kernel (verified).
// ---------------------------------------------------------------------------
__global__ __launch_bounds__(256) void vqc_kernel(
    const float* __restrict__ x, const float* __restrict__ Wproj,
    const float* __restrict__ gmat, const float* __restrict__ Wout,
    const float* __restrict__ bout, float* __restrict__ out, int B) {
    int lane = threadIdx.x & 63;
    int wid  = threadIdx.x >> 6;
    int b    = blockIdx.x * 4 + wid;
    if (b >= B) return;

    const float* xb = x + (size_t)b * 1024;
    float acc[NQ];
#pragma unroll
    for (int q = 0; q < NQ; ++q) acc[q] = 0.f;
#pragma unroll
    for (int k = 0; k < 16; ++k) {
        float xv = xb[k * 64 + lane];
#pragma unroll
        for (int q = 0; q < NQ; ++q)
            acc[q] = fmaf(xv, Wproj[q * 1024 + k * 64 + lane], acc[q]);
    }
#pragma unroll
    for (int q = 0; q < NQ; ++q) acc[q] = wave_sum(acc[q]);

    float cq[NQ], sq[NQ];
#pragma unroll
    for (int q = 0; q < NQ; ++q) {
        float ang = tanhf(acc[q]) * 1.57079632679489662f;
        cq[q] = cosf(0.5f * ang);
        sq[q] = sinf(0.5f * ang);
    }
    float laneprod = 1.f;
#pragma unroll
    for (int q = 4; q < NQ; ++q)
        laneprod *= ((lane >> (q - 4)) & 1) ? sq[q] : cq[q];
    float ar[16], ai[16];
#pragma unroll
    for (int j = 0; j < 16; ++j) {
        float p = laneprod;
#pragma unroll
        for (int q = 0; q < 4; ++q) p *= ((j >> q) & 1) ? sq[q] : cq[q];
        ar[j] = p; ai[j] = 0.f;
    }
    run_circuit(ar, ai, gmat, lane);

    float T = 0.f, S[4] = {0.f, 0.f, 0.f, 0.f};
#pragma unroll
    for (int j = 0; j < 16; ++j) {
        float p = ar[j] * ar[j] + ai[j] * ai[j];
        T += p;
#pragma unroll
        for (int q = 0; q < 4; ++q) S[q] += ((j >> q) & 1) ? -p : p;
    }
    float Zq[NQ];
#pragma unroll
    for (int q = 0; q < 4; ++q) Zq[q] = S[q];
#pragma unroll
    for (int q = 4; q < NQ; ++q) Zq[q] = ((lane >> (q - 4)) & 1) ? -T : T;
#pragma unroll
    for (int q = 0; q < NQ; ++q) Zq[q] = wave_sum(Zq[q]);
    if (lane < NQ) {
        float o = bout[lane];
#pragma unroll
        for (int q = 0; q < NQ; ++q) o = fmaf(Zq[q], Wout[lane * NQ + q], o);
        out[(size_t)b * NQ + lane] = o;
    }
}

extern "C" void kernel_launch(void* const* d_in, const int* in_sizes, int n_in,
                              void* d_out, int out_size, void* d_ws, size_t ws_size,
                              hipStream_t stream) {
    const float* x       = (const float*)d_in[0];
    const float* Wproj   = (const float*)d_in[1];
    const float* weights = (const float*)d_in[2];
    const float* Wout    = (const float*)d_in[3];
    const float* bout    = (const float*)d_in[4];
    float* out = (float*)d_out;
    int B = in_sizes[0] / 1024;

    char* ws = (char*)d_ws;
    size_t off_Bp = 4096;
    size_t off_Bt = off_Bp + (size_t)1024 * 2048 * 2;
    size_t off_V  = off_Bt + (size_t)2048 * 1024 * 2;
    size_t off_Z  = off_V  + (size_t)B * 1024 * 2;
    size_t need   = off_Z  + (size_t)B * 16 * 8 * 4;

    float* gmat = (float*)ws;
    prep_gates_kernel<<<1, 64, 0, stream>>>(weights, gmat);

    if (ws_size >= need && (B % 128) == 0) {
        _Float16* Bp = (_Float16*)(ws + off_Bp);
        _Float16* Bt = (_Float16*)(ws + off_Bt);
        _Float16* V  = (_Float16*)(ws + off_V);
        float*  Zprt = (float*)(ws + off_Z);

        basis_sim_kernel<<<256, 256, 0, stream>>>(gmat, Bp);
        transpose_kernel<<<dim3(32, 16), 256, 0, stream>>>(
            (const unsigned short*)Bp, (unsigned short*)Bt);
        proj_v_kernel<<<B / 4, 256, 0, stream>>>(x, Wproj, V, B);
        gemm_fused_kernel<<<dim3(B / 128, 16), 256, 0, stream>>>(
            (const unsigned short*)V, (const unsigned short*)Bt, Zprt);
        combine_head_kernel<<<B / 4, 256, 0, stream>>>(Zprt, Wout, bout, out, B);
    } else {
        vqc_kernel<<<(B + 3) / 4, 256, 0, stream>>>(x, Wproj, gmat, Wout, bout, out, B);
    }
}

// Round 5
// 172.080 us; speedup vs baseline: 1.7672x; 1.1581x over previous
//
#include <hip/hip_runtime.h>
#include <math.h>
#include <stdint.h>

#define NQ 10
#define DEPTH 6

typedef _Float16 f16x8 __attribute__((ext_vector_type(8)));
typedef float f32x4 __attribute__((ext_vector_type(4)));

typedef __attribute__((address_space(3))) unsigned int lds_u32;
typedef const __attribute__((address_space(1))) unsigned int glb_u32;

// async global->LDS, 16 B per lane; LDS dest = wave-uniform base + lane*16
__device__ __forceinline__ void async_load16(const unsigned short* g, unsigned short* l) {
    __builtin_amdgcn_global_load_lds((glb_u32*)g, (lds_u32*)l, 16, 0, 0);
}

// ---------------------------------------------------------------------------
// Kernel 1: precompute the 60 Rot(phi,theta,omega) 2x2 complex matrices.
// ---------------------------------------------------------------------------
__global__ void prep_gates_kernel(const float* __restrict__ weights,
                                  float* __restrict__ gmat) {
    int idx = blockIdx.x * blockDim.x + threadIdx.x;
    if (idx >= DEPTH * NQ) return;
    float phi   = weights[idx * 3 + 0];
    float theta = weights[idx * 3 + 1];
    float omega = weights[idx * 3 + 2];
    float c = cosf(0.5f * theta), s = sinf(0.5f * theta);
    float ap = -0.5f * (phi + omega);
    float am = -0.5f * (phi - omega);
    float epr = cosf(ap), epi = sinf(ap);
    float emr = cosf(am), emi = sinf(am);
    float* g = gmat + idx * 8;
    g[0] =  epr * c;  g[1] =  epi * c;
    g[2] = -emr * s;  g[3] =  emi * s;
    g[4] =  emr * s;  g[5] =  emi * s;
    g[6] =  epr * c;  g[7] = -epi * c;
}

// ---------------------------------------------------------------------------
// Circuit core: one wave holds 1024 amps. bits 0..3 slot, 4..9 lane.
// All cross-lane shuffles of a gate are issued BEFORE any use, so the
// ~120cyc DS latency is paid once per gate, not once per slot.
// ---------------------------------------------------------------------------
__device__ __forceinline__ void apply_1q_local(
    float (&ar)[16], float (&ai)[16], int q,
    float u00r, float u00i, float u01r, float u01i,
    float u10r, float u10i, float u11r, float u11i) {
#pragma unroll
    for (int j = 0; j < 16; ++j) {
        if ((j >> q) & 1) continue;
        int j1 = j | (1 << q);
        float a0r = ar[j],  a0i = ai[j];
        float a1r = ar[j1], a1i = ai[j1];
        ar[j]  = u00r*a0r - u00i*a0i + u01r*a1r - u01i*a1i;
        ai[j]  = u00r*a0i + u00i*a0r + u01r*a1i + u01i*a1r;
        ar[j1] = u10r*a0r - u10i*a0i + u11r*a1r - u11i*a1i;
        ai[j1] = u10r*a0i + u10i*a0r + u11r*a1i + u11i*a1r;
    }
}

__device__ __forceinline__ void apply_1q_lane(
    float (&ar)[16], float (&ai)[16], int q, int lane,
    float u00r, float u00i, float u01r, float u01i,
    float u10r, float u10i, float u11r, float u11i) {
    int  m  = 1 << (q - 4);
    bool hi = (lane >> (q - 4)) & 1;
    float car = hi ? u11r : u00r, cai = hi ? u11i : u00i;
    float cbr = hi ? u10r : u01r, cbi = hi ? u10i : u01i;
    float pr[16], pi[16];
#pragma unroll
    for (int j = 0; j < 16; ++j) pr[j] = __shfl_xor(ar[j], m, 64);
#pragma unroll
    for (int j = 0; j < 16; ++j) pi[j] = __shfl_xor(ai[j], m, 64);
#pragma unroll
    for (int j = 0; j < 16; ++j) {
        float mr = ar[j], mi = ai[j];
        ar[j] = car*mr - cai*mi + cbr*pr[j] - cbi*pi[j];
        ai[j] = car*mi + cai*mr + cbr*pi[j] + cbi*pr[j];
    }
}

__device__ __forceinline__ void cnot_gate(
    float (&ar)[16], float (&ai)[16], int c, int t, int lane) {
    if (c < 4 && t < 4) {                    // both local: register permutation
#pragma unroll
        for (int j = 0; j < 16; ++j) {
            if (((j >> c) & 1) && !((j >> t) & 1)) {
                int j1 = j | (1 << t);
                float tr = ar[j]; ar[j] = ar[j1]; ar[j1] = tr;
                float ti = ai[j]; ai[j] = ai[j1]; ai[j1] = ti;
            }
        }
    } else if (c < 4) {                      // control local, target lane
        int m = 1 << (t - 4);
        float pr[16], pi[16];
#pragma unroll
        for (int j = 0; j < 16; ++j)
            if ((j >> c) & 1) pr[j] = __shfl_xor(ar[j], m, 64);
#pragma unroll
        for (int j = 0; j < 16; ++j)
            if ((j >> c) & 1) pi[j] = __shfl_xor(ai[j], m, 64);
#pragma unroll
        for (int j = 0; j < 16; ++j)
            if ((j >> c) & 1) { ar[j] = pr[j]; ai[j] = pi[j]; }
    } else if (t < 4) {                      // control lane, target local
        bool cb = (lane >> (c - 4)) & 1;
#pragma unroll
        for (int j = 0; j < 16; ++j) {
            if (!((j >> t) & 1)) {
                int j1 = j | (1 << t);
                float lr = ar[j], li = ai[j], hr = ar[j1], hi2 = ai[j1];
                ar[j]  = cb ? hr : lr;  ai[j]  = cb ? hi2 : li;
                ar[j1] = cb ? lr : hr;  ai[j1] = cb ? li : hi2;
            }
        }
    } else {                                 // both lane
        int  m  = 1 << (t - 4);
        bool cb = (lane >> (c - 4)) & 1;
        float pr[16], pi[16];
#pragma unroll
        for (int j = 0; j < 16; ++j) pr[j] = __shfl_xor(ar[j], m, 64);
#pragma unroll
        for (int j = 0; j < 16; ++j) pi[j] = __shfl_xor(ai[j], m, 64);
#pragma unroll
        for (int j = 0; j < 16; ++j) {
            ar[j] = cb ? pr[j] : ar[j];
            ai[j] = cb ? pi[j] : ai[j];
        }
    }
}

template <int R>
__device__ __forceinline__ void cnot_ring(float (&ar)[16], float (&ai)[16], int lane) {
#pragma unroll
    for (int i = 0; i < NQ; ++i) cnot_gate(ar, ai, i, (i + R) % NQ, lane);
}

__device__ __forceinline__ void run_circuit(float (&ar)[16], float (&ai)[16],
                                            const float* __restrict__ gmat, int lane) {
    for (int l = 0; l < DEPTH; ++l) {
        const float* gl = gmat + l * (NQ * 8);
#pragma unroll
        for (int i = 0; i < NQ; ++i) {
            const float* g = gl + i * 8;
            float u00r = g[0], u00i = g[1], u01r = g[2], u01i = g[3];
            float u10r = g[4], u10i = g[5], u11r = g[6], u11i = g[7];
            if (i < 4)
                apply_1q_local(ar, ai, i, u00r,u00i,u01r,u01i,u10r,u10i,u11r,u11i);
            else
                apply_1q_lane(ar, ai, i, lane, u00r,u00i,u01r,u01i,u10r,u10i,u11r,u11i);
        }
        switch (l) {
            case 0: cnot_ring<1>(ar, ai, lane); break;
            case 1: cnot_ring<2>(ar, ai, lane); break;
            case 2: cnot_ring<3>(ar, ai, lane); break;
            case 3: cnot_ring<4>(ar, ai, lane); break;
            case 4: cnot_ring<5>(ar, ai, lane); break;
            default: cnot_ring<6>(ar, ai, lane); break;
        }
    }
}

__device__ __forceinline__ float wave_sum(float v) {
#pragma unroll
    for (int m = 1; m < 64; m <<= 1) v += __shfl_xor(v, m, 64);
    return v;
}

// ---------------------------------------------------------------------------
// Device bodies for the fused basis+proj kernel.
// ---------------------------------------------------------------------------
__device__ __forceinline__ void basis_sim_body(
    const float* __restrict__ gmat, _Float16* __restrict__ Bp, int h, int lane) {
    float ar[16], ai[16];
#pragma unroll
    for (int j = 0; j < 16; ++j) {
        ar[j] = (lane == (h >> 4) && j == (h & 15)) ? 1.f : 0.f;
        ai[j] = 0.f;
    }
    run_circuit(ar, ai, gmat, lane);

    unsigned int buf[16];
#pragma unroll
    for (int j = 0; j < 16; ++j) {
        unsigned short r16 = __builtin_bit_cast(unsigned short, (_Float16)ar[j]);
        unsigned short i16 = __builtin_bit_cast(unsigned short, (_Float16)ai[j]);
        buf[j] = (unsigned int)r16 | ((unsigned int)i16 << 16);
    }
    uint4* dst = (uint4*)(Bp + (size_t)h * 2048 + 32 * lane);
#pragma unroll
    for (int k = 0; k < 4; ++k) {
        uint4 v; v.x = buf[k*4+0]; v.y = buf[k*4+1]; v.z = buf[k*4+2]; v.w = buf[k*4+3];
        dst[k] = v;
    }
}

__device__ __forceinline__ void proj_v_body(
    const float* __restrict__ x, const float* __restrict__ Wproj,
    _Float16* __restrict__ V, int b, int lane) {
    const float* xb = x + (size_t)b * 1024;
    float acc[NQ];
#pragma unroll
    for (int q = 0; q < NQ; ++q) acc[q] = 0.f;
#pragma unroll
    for (int k = 0; k < 16; ++k) {
        float xv = xb[k * 64 + lane];
#pragma unroll
        for (int q = 0; q < NQ; ++q)
            acc[q] = fmaf(xv, Wproj[q * 1024 + k * 64 + lane], acc[q]);
    }
#pragma unroll
    for (int q = 0; q < NQ; ++q) acc[q] = wave_sum(acc[q]);

    float cq[NQ], sq[NQ];
#pragma unroll
    for (int q = 0; q < NQ; ++q) {
        float ang = tanhf(acc[q]) * 1.57079632679489662f;
        cq[q] = cosf(0.5f * ang);
        sq[q] = sinf(0.5f * ang);
    }
    float laneprod = 1.f;
#pragma unroll
    for (int q = 4; q < NQ; ++q)
        laneprod *= ((lane >> (q - 4)) & 1) ? sq[q] : cq[q];

    unsigned int buf[8];
#pragma unroll
    for (int jj = 0; jj < 8; ++jj) {
        unsigned short h2[2];
#pragma unroll
        for (int c = 0; c < 2; ++c) {
            int j = jj * 2 + c;
            float p = laneprod;
#pragma unroll
            for (int q = 0; q < 4; ++q) p *= ((j >> q) & 1) ? sq[q] : cq[q];
            h2[c] = __builtin_bit_cast(unsigned short, (_Float16)p);
        }
        buf[jj] = (unsigned int)h2[0] | ((unsigned int)h2[1] << 16);
    }
    uint4* dst = (uint4*)(V + (size_t)b * 1024 + 16 * lane);
    uint4 v0; v0.x = buf[0]; v0.y = buf[1]; v0.z = buf[2]; v0.w = buf[3];
    uint4 v1; v1.x = buf[4]; v1.y = buf[5]; v1.z = buf[6]; v1.w = buf[7];
    dst[0] = v0; dst[1] = v1;
}

// ---------------------------------------------------------------------------
// Kernel 2: fused basis sim (first 256 blocks) + projection (rest).
// Independent work; fusing lets proj fill CUs while basis runs latency-bound.
// ---------------------------------------------------------------------------
__global__ __launch_bounds__(256) void basis_proj_kernel(
    const float* __restrict__ gmat, _Float16* __restrict__ Bp,
    const float* __restrict__ x, const float* __restrict__ Wproj,
    _Float16* __restrict__ V, int B) {
    int lane = threadIdx.x & 63;
    int wid  = threadIdx.x >> 6;
    if (blockIdx.x < 256) {
        int h = blockIdx.x * 4 + wid;
        basis_sim_body(gmat, Bp, h, lane);
    } else {
        int b = (blockIdx.x - 256) * 4 + wid;
        if (b < B) proj_v_body(x, Wproj, V, b, lane);
    }
}

// ---------------------------------------------------------------------------
// Kernel 3: transpose B' (1024 x 2048) -> Bt (2048 x 1024)
// ---------------------------------------------------------------------------
__global__ __launch_bounds__(256) void transpose_kernel(
    const unsigned short* __restrict__ src, unsigned short* __restrict__ dst) {
    __shared__ unsigned short tile[64][65];
    int bx = blockIdx.x;
    int by = blockIdx.y;
    int tx = threadIdx.x & 63;
    int ty = threadIdx.x >> 6;
#pragma unroll
    for (int i = 0; i < 16; ++i) {
        int r = ty + i * 4;
        tile[r][tx] = src[(size_t)(by*64 + r) * 2048 + bx*64 + tx];
    }
    __syncthreads();
#pragma unroll
    for (int i = 0; i < 16; ++i) {
        int r = ty + i * 4;
        dst[(size_t)(bx*64 + r) * 1024 + by*64 + tx] = tile[tx][r];
    }
}

// ---------------------------------------------------------------------------
// Kernel 4: fused GEMM + |psi|^2 + partial-Z reduction (verified round 4).
// ---------------------------------------------------------------------------
__global__ __launch_bounds__(256) void gemm_fused_kernel(
    const unsigned short* __restrict__ A,    // V (B,1024)
    const unsigned short* __restrict__ Bt,   // (2048,1024)
    float* __restrict__ Zpart) {             // (B,16,8)
    __shared__ unsigned short As[128 * 64];
    __shared__ unsigned short Bs[128 * 64];
    int tid  = threadIdx.x;
    int lane = tid & 63;
    int w    = tid >> 6;
    int m0   = blockIdx.x * 128;
    int n0   = blockIdx.y * 128;
    int mh   = (w >> 1) * 64, nh = (w & 1) * 64;
    int quad = lane >> 4;
    int lrow = lane & 15;

    int srow  = (lane >> 3);
    int schnk = (lane & 7) ^ srow;

    f32x4 acc[4][4];
#pragma unroll
    for (int mi = 0; mi < 4; ++mi)
#pragma unroll
        for (int ni = 0; ni < 4; ++ni)
            acc[mi][ni] = (f32x4){0.f, 0.f, 0.f, 0.f};

    for (int kt = 0; kt < 16; ++kt) {
        if (kt) __syncthreads();
#pragma unroll
        for (int r = 0; r < 4; ++r) {
            int s   = w * 4 + r;
            int row = s * 8 + srow;
            async_load16(A  + (size_t)(m0 + row) * 1024 + kt * 64 + schnk * 8,
                         As + s * 512);
            async_load16(Bt + (size_t)(n0 + row) * 1024 + kt * 64 + schnk * 8,
                         Bs + s * 512);
        }
        asm volatile("s_waitcnt vmcnt(0)" ::: "memory");
        __syncthreads();
#pragma unroll
        for (int kk = 0; kk < 2; ++kk) {
            f16x8 af[4], bf[4];
#pragma unroll
            for (int i = 0; i < 4; ++i) {
                int cxa = (kk * 4 + quad) ^ (lrow & 7);
                af[i] = *(const f16x8*)(As + (mh + i * 16 + lrow) * 64 + cxa * 8);
                bf[i] = *(const f16x8*)(Bs + (nh + i * 16 + lrow) * 64 + cxa * 8);
            }
#pragma unroll
            for (int mi = 0; mi < 4; ++mi)
#pragma unroll
                for (int ni = 0; ni < 4; ++ni)
                    acc[mi][ni] = __builtin_amdgcn_mfma_f32_16x16x32_f16(
                        af[mi], bf[ni], acc[mi][ni], 0, 0, 0);
        }
    }

    __syncthreads();
    float* Zs = (float*)As;
#pragma unroll
    for (int mi = 0; mi < 4; ++mi) {
#pragma unroll
        for (int r = 0; r < 4; ++r) {
            float p0 = acc[mi][0][r] * acc[mi][0][r];
            float p1 = acc[mi][1][r] * acc[mi][1][r];
            float p2 = acc[mi][2][r] * acc[mi][2][r];
            float p3 = acc[mi][3][r] * acc[mi][3][r];
            float t0 = (p0 + p1) + (p2 + p3);
            float t3 = (p0 - p1) + (p2 - p3);
            float t4 = (p0 + p1) - (p2 + p3);
            t0 += __shfl_xor(t0, 1, 64);
            t3 += __shfl_xor(t3, 1, 64);
            t4 += __shfl_xor(t4, 1, 64);
            float u2 = __shfl_xor(t0, 2, 64);
            float ap = t0 + u2;
            float am = (lane & 2) ? u2 - t0 : t0 - u2;
            t3 += __shfl_xor(t3, 2, 64);
            t4 += __shfl_xor(t4, 2, 64);
            float u4  = __shfl_xor(ap, 4, 64);
            float bpp = ap + u4;
            float bpm = (lane & 4) ? u4 - ap : ap - u4;
            float bmp = am + __shfl_xor(am, 4, 64);
            t3 += __shfl_xor(t3, 4, 64);
            t4 += __shfl_xor(t4, 4, 64);
            float u8 = __shfl_xor(bpp, 8, 64);
            float T  = bpp + u8;
            float Z2 = (lane & 8) ? u8 - bpp : bpp - u8;
            float Z1 = bpm + __shfl_xor(bpm, 8, 64);
            float Z0 = bmp + __shfl_xor(bmp, 8, 64);
            t3 += __shfl_xor(t3, 8, 64);
            t4 += __shfl_xor(t4, 8, 64);
            if (lrow == 0) {
                int row = mh + mi * 16 + quad * 4 + r;
                float* z = Zs + ((size_t)(w & 1) * 128 + row) * 8;
                z[0] = T;  z[1] = Z0; z[2] = Z1; z[3] = Z2;
                z[4] = t3; z[5] = t4;
            }
        }
    }
    __syncthreads();
    {
        int row  = tid >> 1, part = tid & 1;
        const float* za = Zs + (size_t)row * 8;
        const float* zb = Zs + (size_t)(128 + row) * 8;
        float o[4];
        if (part == 0) {
            o[0] = za[0] + zb[0];
            o[1] = za[1] + zb[1];
            o[2] = za[2] + zb[2];
            o[3] = za[3] + zb[3];
        } else {
            o[0] = za[4] + zb[4];
            o[1] = za[5] + zb[5];
            o[2] = za[0] - zb[0];
            o[3] = 0.f;
        }
        float4 v = {o[0], o[1], o[2], o[3]};
        *(float4*)(Zpart + ((size_t)(m0 + row) * 16 + blockIdx.y) * 8 + part * 4) = v;
    }
}

// ---------------------------------------------------------------------------
// Kernel 5: combine 16 n-tile partials -> Z_q -> output head.
// ---------------------------------------------------------------------------
__global__ __launch_bounds__(256) void combine_head_kernel(
    const float* __restrict__ Zpart, const float* __restrict__ Wout,
    const float* __restrict__ bout, float* __restrict__ out, int B) {
    int lane = threadIdx.x & 63;
    int wid  = threadIdx.x >> 6;
    int b    = blockIdx.x * 4 + wid;
    if (b >= B) return;

    float z[8];
    if (lane < 16) {
        const float4* p = (const float4*)(Zpart + ((size_t)b * 16 + lane) * 8);
        float4 a = p[0], c = p[1];
        z[0]=a.x; z[1]=a.y; z[2]=a.z; z[3]=a.w; z[4]=c.x; z[5]=c.y; z[6]=c.z; z[7]=c.w;
    } else {
#pragma unroll
        for (int i = 0; i < 8; ++i) z[i] = 0.f;
    }
    float Zq[NQ];
#pragma unroll
    for (int q = 0; q < 6; ++q) {
        float v = z[q + 1];
        v += __shfl_xor(v, 1, 64);
        v += __shfl_xor(v, 2, 64);
        v += __shfl_xor(v, 4, 64);
        v += __shfl_xor(v, 8, 64);
        Zq[q] = v;
    }
    {
        float T = z[0];
        float u1 = __shfl_xor(T, 1, 64);
        float P  = T + u1;
        float M  = (lane & 1) ? u1 - T : T - u1;
        float u2 = __shfl_xor(P, 2, 64);
        float PP = P + u2;
        float PM = (lane & 2) ? u2 - P : P - u2;
        float MP = M + __shfl_xor(M, 2, 64);
        float u4  = __shfl_xor(PP, 4, 64);
        float PPP = PP + u4;
        float PPM = (lane & 4) ? u4 - PP : PP - u4;
        float PMP = PM + __shfl_xor(PM, 4, 64);
        float MPP = MP + __shfl_xor(MP, 4, 64);
        float u8 = __shfl_xor(PPP, 8, 64);
        Zq[9] = (lane & 8) ? u8 - PPP : PPP - u8;
        Zq[8] = PPM + __shfl_xor(PPM, 8, 64);
        Zq[7] = PMP + __shfl_xor(PMP, 8, 64);
        Zq[6] = MPP + __shfl_xor(MPP, 8, 64);
    }
    if (lane < NQ) {
        float o = bout[lane];
#pragma unroll
        for (int q = 0; q < NQ; ++q) o = fmaf(Zq[q], Wout[lane * NQ + q], o);
        out[(size_t)b * NQ + lane] = o;
    }
}

// ---------------------------------------------------------------------------
// Fallback: round-1 monolithic kernel (verified).
// ---------------------------------------------------------------------------
__global__ __launch_bounds__(256) void vqc_kernel(
    const float* __restrict__ x, const float* __restrict__ Wproj,
    const float* __restrict__ gmat, const float* __restrict__ Wout,
    const float* __restrict__ bout, float* __restrict__ out, int B) {
    int lane = threadIdx.x & 63;
    int wid  = threadIdx.x >> 6;
    int b    = blockIdx.x * 4 + wid;
    if (b >= B) return;

    const float* xb = x + (size_t)b * 1024;
    float acc[NQ];
#pragma unroll
    for (int q = 0; q < NQ; ++q) acc[q] = 0.f;
#pragma unroll
    for (int k = 0; k < 16; ++k) {
        float xv = xb[k * 64 + lane];
#pragma unroll
        for (int q = 0; q < NQ; ++q)
            acc[q] = fmaf(xv, Wproj[q * 1024 + k * 64 + lane], acc[q]);
    }
#pragma unroll
    for (int q = 0; q < NQ; ++q) acc[q] = wave_sum(acc[q]);

    float cq[NQ], sq[NQ];
#pragma unroll
    for (int q = 0; q < NQ; ++q) {
        float ang = tanhf(acc[q]) * 1.57079632679489662f;
        cq[q] = cosf(0.5f * ang);
        sq[q] = sinf(0.5f * ang);
    }
    float laneprod = 1.f;
#pragma unroll
    for (int q = 4; q < NQ; ++q)
        laneprod *= ((lane >> (q - 4)) & 1) ? sq[q] : cq[q];
    float ar[16], ai[16];
#pragma unroll
    for (int j = 0; j < 16; ++j) {
        float p = laneprod;
#pragma unroll
        for (int q = 0; q < 4; ++q) p *= ((j >> q) & 1) ? sq[q] : cq[q];
        ar[j] = p; ai[j] = 0.f;
    }
    run_circuit(ar, ai, gmat, lane);

    float T = 0.f, S[4] = {0.f, 0.f, 0.f, 0.f};
#pragma unroll
    for (int j = 0; j < 16; ++j) {
        float p = ar[j] * ar[j] + ai[j] * ai[j];
        T += p;
#pragma unroll
        for (int q = 0; q < 4; ++q) S[q] += ((j >> q) & 1) ? -p : p;
    }
    float Zq[NQ];
#pragma unroll
    for (int q = 0; q < 4; ++q) Zq[q] = S[q];
#pragma unroll
    for (int q = 4; q < NQ; ++q) Zq[q] = ((lane >> (q - 4)) & 1) ? -T : T;
#pragma unroll
    for (int q = 0; q < NQ; ++q) Zq[q] = wave_sum(Zq[q]);
    if (lane < NQ) {
        float o = bout[lane];
#pragma unroll
        for (int q = 0; q < NQ; ++q) o = fmaf(Zq[q], Wout[lane * NQ + q], o);
        out[(size_t)b * NQ + lane] = o;
    }
}

extern "C" void kernel_launch(void* const* d_in, const int* in_sizes, int n_in,
                              void* d_out, int out_size, void* d_ws, size_t ws_size,
                              hipStream_t stream) {
    const float* x       = (const float*)d_in[0];
    const float* Wproj   = (const float*)d_in[1];
    const float* weights = (const float*)d_in[2];
    const float* Wout    = (const float*)d_in[3];
    const float* bout    = (const float*)d_in[4];
    float* out = (float*)d_out;
    int B = in_sizes[0] / 1024;

    char* ws = (char*)d_ws;
    size_t off_Bp = 4096;
    size_t off_Bt = off_Bp + (size_t)1024 * 2048 * 2;
    size_t off_V  = off_Bt + (size_t)2048 * 1024 * 2;
    size_t off_Z  = off_V  + (size_t)B * 1024 * 2;
    size_t need   = off_Z  + (size_t)B * 16 * 8 * 4;

    float* gmat = (float*)ws;
    prep_gates_kernel<<<1, 64, 0, stream>>>(weights, gmat);

    if (ws_size >= need && (B % 128) == 0) {
        _Float16* Bp = (_Float16*)(ws + off_Bp);
        _Float16* Bt = (_Float16*)(ws + off_Bt);
        _Float16* V  = (_Float16*)(ws + off_V);
        float*  Zprt = (float*)(ws + off_Z);

        basis_proj_kernel<<<256 + B / 4, 256, 0, stream>>>(gmat, Bp, x, Wproj, V, B);
        transpose_kernel<<<dim3(32, 16), 256, 0, stream>>>(
            (const unsigned short*)Bp, (unsigned short*)Bt);
        gemm_fused_kernel<<<dim3(B / 128, 16), 256, 0, stream>>>(
            (const unsigned short*)V, (const unsigned short*)Bt, Zprt);
        combine_head_kernel<<<B / 4, 256, 0, stream>>>(Zprt, Wout, bout, out, B);
    } else {
        vqc_kernel<<<(B + 3) / 4, 256, 0, stream>>>(x, Wproj, gmat, Wout, bout, out, B);
    }
}